// Round 20
// baseline (140.837 us; speedup 1.0000x reference)
//
#include <hip/hip_runtime.h>
#include <hip/hip_bf16.h>

typedef __attribute__((ext_vector_type(8))) _Float16 half8;   // 8 f16 = 4 VGPRs
typedef __attribute__((ext_vector_type(4))) _Float16 half4;   // 4 f16 = 8 B
typedef __attribute__((ext_vector_type(4))) float f32x4;
typedef __attribute__((ext_vector_type(16))) float f32x16;
typedef __attribute__((ext_vector_type(2))) unsigned uint2v;
typedef __attribute__((ext_vector_type(4))) unsigned uint4v;

#define MFMAH(a, b, c) __builtin_amdgcn_mfma_f32_16x16x32_f16((a), (b), (c), 0, 0, 0)
#define MFMA32(a, b, c) __builtin_amdgcn_mfma_f32_32x32x16_f16((a), (b), (c), 0, 0, 0)

__device__ __forceinline__ short f2h(float v) { _Float16 h = (_Float16)v; return __builtin_bit_cast(short, h); }
__device__ __forceinline__ f32x4 fzero() { f32x4 z = {0.f, 0.f, 0.f, 0.f}; return z; }
__device__ __forceinline__ float u2f(unsigned u) { return __builtin_bit_cast(float, u); }
__device__ __forceinline__ unsigned f2u(float f) { return __builtin_bit_cast(unsigned, f); }

__device__ __forceinline__ void gl16(const void* g, void* l) {
    __builtin_amdgcn_global_load_lds((const __attribute__((address_space(1))) unsigned*)g,
                                     (__attribute__((address_space(3))) unsigned*)l, 16, 0, 0);
}

__device__ __forceinline__ float fast_tanh(float z) {
    // 1 - 2/(e^2z + 1): saturates to exactly +-1.0, err ~1e-6
    float E = __expf(2.f * z);
    return 1.f - 2.f / (E + 1.f);
}

__device__ __forceinline__ float gelu_tanh(float v) {
    float u = 0.7978845608028654f * (v + 0.044715f * v * v * v);
    return 0.5f * v * (1.f + fast_tanh(u));
}

// ---------------- fused prep: W transposes + f16 bilinear quad table ----------------

__global__ __launch_bounds__(256) void prep_all_k(
    const float* __restrict__ x, const float* __restrict__ Woff2,
    const float* __restrict__ Wq, const float* __restrict__ Wk, const float* __restrict__ Wv,
    const float* __restrict__ Wo,
    short* __restrict__ B2T, short* __restrict__ Wtqkv, short* __restrict__ WtoT,
    half4* __restrict__ Q)
{
    __shared__ float t[64][65];
    const int tid = threadIdx.x;
    const int bid = blockIdx.x;
    if (bid < 256) {
        const int bk = bid >> 6, bn = bid & 63;
        const int k0 = bk * 64, n0 = bn * 64;
#pragma unroll
        for (int p = 0; p < 16; ++p) {
            int idx = p * 256 + tid, r = idx >> 6, c = idx & 63;
            t[r][c] = Woff2[(long)(k0 + r) * 4096 + n0 + c];
        }
        __syncthreads();
#pragma unroll
        for (int p = 0; p < 16; ++p) {
            int idx = p * 256 + tid, nr = idx >> 6, kc = idx & 63;
            float v = t[kc][nr];
            _Float16 w1 = (_Float16)v;
            _Float16 w2 = (_Float16)(v - (float)w1);
            long base = (long)(n0 + nr) * 768 + k0 + kc;
            B2T[base]       = __builtin_bit_cast(short, w1);
            B2T[base + 256] = __builtin_bit_cast(short, w1);
            B2T[base + 512] = __builtin_bit_cast(short, w2);
        }
    } else if (bid < 1024) {
        int i = (bid - 256) * 256 + tid;           // 768*256
        int n = i >> 8, k = i & 255;
        const float* s = (n < 256) ? Wq : (n < 512) ? Wk : Wv;
        Wtqkv[i] = f2h(s[k * 256 + (n & 255)]);
    } else if (bid < 3072) {
        int i = (bid - 1024) * 256 + tid;          // 256*2048
        int n = i >> 11, k = i & 2047;
        WtoT[i] = f2h(Wo[k * 256 + n]);
    } else {
        int i = (bid - 3072) * 256 + tid;          // 2*1024*256
        int b = i >> 18, r = (i >> 8) & 1023, c = i & 255;
        const float* xb = x + (b << 18);
        int r1 = (r + 1) & 1023, c1 = (c + 1) & 255;
        half4 qv;
        qv[0] = (_Float16)xb[(r << 8) + c];
        qv[1] = (_Float16)xb[(r << 8) + c1];
        qv[2] = (_Float16)xb[(r1 << 8) + c];
        qv[3] = (_Float16)xb[(r1 << 8) + c1];
        Q[i] = qv;
    }
}

// ---------------- GEMM1: exact fp32, fused gelu + fp16 hi/lo split ----------------

__global__ __launch_bounds__(256) void gemm1_k(const float* __restrict__ x, const float* __restrict__ W,
                                               const float* __restrict__ bias, short* __restrict__ hs) {
    __shared__ float As[64][17];
    __shared__ float Bs[16][68];
    const int tid = threadIdx.x;
    const int bm = blockIdx.x >> 2, bn = blockIdx.x & 3;     // 32 x 4
    const int m0 = bm * 64, n0 = bn * 64;
    const int ty = tid >> 4, tx = tid & 15;
    float acc[4][4] = {};
    const int ar = tid >> 2, ak = (tid & 3) << 2;
    const int bk = tid >> 4, bc = (tid & 15) << 2;

    for (int k0 = 0; k0 < 256; k0 += 16) {
        __syncthreads();
        float4 av = *(const float4*)(x + (m0 + ar) * 256 + k0 + ak);
        As[ar][ak + 0] = av.x; As[ar][ak + 1] = av.y; As[ar][ak + 2] = av.z; As[ar][ak + 3] = av.w;
        *(float4*)&Bs[bk][bc] = *(const float4*)(W + (k0 + bk) * 256 + n0 + bc);
        __syncthreads();
#pragma unroll
        for (int kk = 0; kk < 16; ++kk) {
            float a_[4], b_[4];
#pragma unroll
            for (int i = 0; i < 4; ++i) a_[i] = As[ty * 4 + i][kk];
            *(float4*)b_ = *(const float4*)&Bs[kk][tx * 4];
#pragma unroll
            for (int i = 0; i < 4; ++i)
#pragma unroll
                for (int j = 0; j < 4; ++j) acc[i][j] += a_[i] * b_[j];
        }
    }
#pragma unroll
    for (int i = 0; i < 4; ++i) {
        int row = m0 + ty * 4 + i;
#pragma unroll
        for (int j = 0; j < 4; ++j) {
            int col = n0 + tx * 4 + j;
            float v = gelu_tanh(acc[i][j] + bias[col]);
            _Float16 h1 = (_Float16)v;
            _Float16 h2 = (_Float16)(v - (float)h1);
            hs[row * 768 + col]       = __builtin_bit_cast(short, h1);
            hs[row * 768 + 256 + col] = __builtin_bit_cast(short, h2);
            hs[row * 768 + 512 + col] = __builtin_bit_cast(short, h1);
        }
    }
}

// ---------------- offset GEMM: 128x128, counted-vmcnt dbuf; writes fp32 z ----------------
// z = x@W2 + b2 (pre-tanh) -> oz [2048][4096] fp32, LDS-staged coalesced stores.

__global__ __launch_bounds__(256, 3) void gemm_off(
    const short* __restrict__ A, const short* __restrict__ BT,
    const float* __restrict__ b0, float* __restrict__ oz)
{
    __shared__ short lds[16384];          // 32 KB
    short* As0 = lds;
    short* As1 = lds + 4096;
    short* Bs0 = lds + 8192;
    short* Bs1 = lds + 12288;

    const int tid = threadIdx.x;
    const int lane = tid & 63, w = tid >> 6;
    const int rl = lane & 15, g = lane >> 4;
    const int wr = w >> 1, wc = w & 1;
    const int bid = blockIdx.x;
    const int g2 = bid & 7, s = bid >> 3;
    const int bm = (g2 >> 2) * 8 + (s >> 3);
    const int bn = (g2 & 3) * 8 + (s & 7);
    const int m0 = bm << 7, n0 = bn << 7;

    f32x4 acc[4][4];
#pragma unroll
    for (int m = 0; m < 4; ++m)
#pragma unroll
        for (int n = 0; n < 4; ++n) acc[m][n] = fzero();

    const short* ap = A + (long)(m0 + w * 32 + (lane >> 2)) * 768 + ((lane & 3) << 3);
    const short* bp = BT + (long)(n0 + w * 32 + (lane >> 2)) * 768 + ((lane & 3) << 3);
    const int woff = w * 1024;

#define STAGE(dA, dB, kk) do { \
        gl16(ap + (kk), (dA) + woff); \
        gl16(ap + (kk) + 16 * 768, (dA) + woff + 512); \
        gl16(bp + (kk), (dB) + woff); \
        gl16(bp + (kk) + 16 * 768, (dB) + woff + 512); } while (0)

    STAGE(As0, Bs0, 0);
    for (int t = 0; t < 24; ++t) {
        const short* cA = (t & 1) ? As1 : As0;
        const short* cB = (t & 1) ? Bs1 : Bs0;
        short* nA = (t & 1) ? As0 : As1;
        short* nB = (t & 1) ? Bs0 : Bs1;
        if (t + 1 < 24) {
            STAGE(nA, nB, (t + 1) << 5);
            asm volatile("s_waitcnt vmcnt(4)" ::: "memory");
        } else {
            asm volatile("s_waitcnt vmcnt(0)" ::: "memory");
        }
        __builtin_amdgcn_s_barrier();
        half8 af[4], bf[4];
#pragma unroll
        for (int m = 0; m < 4; ++m) af[m] = *(const half8*)&cA[(wr * 64 + m * 16 + rl) * 32 + g * 8];
#pragma unroll
        for (int n = 0; n < 4; ++n) bf[n] = *(const half8*)&cB[(wc * 64 + n * 16 + rl) * 32 + g * 8];
#pragma unroll
        for (int m = 0; m < 4; ++m)
#pragma unroll
            for (int n = 0; n < 4; ++n) acc[m][n] = MFMAH(af[m], bf[n], acc[m][n]);
        __builtin_amdgcn_s_barrier();
    }
#undef STAGE

    // epilogue: z = acc + bias -> fp32, 2-pass LDS staging (64x128 f32 = 32KB)
    float* ldsf = (float*)lds;
#pragma unroll
    for (int pass = 0; pass < 2; ++pass) {
        __syncthreads();
        if (wr == pass) {
#pragma unroll
            for (int m = 0; m < 4; ++m)
#pragma unroll
                for (int nt = 0; nt < 4; ++nt) {
                    const int cl = wc * 64 + nt * 16 + rl;
                    const float bb = b0[n0 + cl];
#pragma unroll
                    for (int j = 0; j < 4; ++j)
                        ldsf[(m * 16 + g * 4 + j) * 128 + cl] = acc[m][nt][j] + bb;
                }
        }
        __syncthreads();
        float* oo = oz + (long)(m0 + pass * 64) * 4096 + n0;
#pragma unroll
        for (int p = 0; p < 8; ++p) {
            int idx = p * 256 + tid, rowl = idx >> 5, ch = idx & 31;
            *(float4*)(oo + rowl * 4096 + ch * 4) = *(const float4*)&ldsf[rowl * 128 + ch * 4];
        }
    }
}

// ---------------- sampler: full-occupancy quad-gather (no LDS, no barriers) ----------------
// Block = one token (batch,t) x 8 heads x 256 channels; thread = 8 samples.
// XCD-aligned: bid&7 = XCD -> batch = (bid&7)>>2; Q slice (2MB) L2-resident.

__global__ __launch_bounds__(256) void sample_k(const float* __restrict__ oz,
                                                const half4* __restrict__ Q,
                                                short* __restrict__ xs) {
    const int tid = threadIdx.x, bid = blockIdx.x;
    const int xcd = bid & 7, batch = xcd >> 2;
    const int t = (xcd & 3) * 256 + (bid >> 3);    // token within batch [0,1024)
    const int d = tid >> 5, c0 = (tid & 31) * 8;
    const float* orow = oz + (long)(batch * 1024 + t) * 4096 + d * 512 + c0 * 2;
    float o[16];
    *(float4*)&o[0]  = *(const float4*)(orow + 0);
    *(float4*)&o[4]  = *(const float4*)(orow + 4);
    *(float4*)&o[8]  = *(const float4*)(orow + 8);
    *(float4*)&o[12] = *(const float4*)(orow + 12);
    const half4* Qb = Q + ((long)batch << 18);
    short res[8];
#pragma unroll
    for (int i = 0; i < 8; ++i) {
        float gx = (fast_tanh(o[2 * i]) + 1.f) * 127.5f;        // [0,255]
        float gy = (fast_tanh(o[2 * i + 1]) + 1.f) * 4095.5f;   // [0,8191]
        float x0f = floorf(gx), y0f = floorf(gy);
        float wx = gx - x0f, wy = gy - y0f;
        int ix0 = (int)x0f, iy0 = (int)y0f;
        half4 qv = Qb[((iy0 & 1023) << 8) + ix0];
        res[i] = f2h((float)qv[0] * (1.f - wy) * (1.f - wx) + (float)qv[1] * (1.f - wy) * wx
                   + (float)qv[2] * wy * (1.f - wx) + (float)qv[3] * wy * wx);
    }
    *(half8*)(xs + ((long)(batch * 8 + d) * 1024 + t) * 256 + c0) = *(half8*)res;
}

// ---------------- 128x128 MFMA GEMM, counted-vmcnt double-buffered staging ----------------
// EPI 2: qkv scatter, LDS-staged final layouts
// EPI 3: fp32 split-K partial (blockIdx.y = ks)

template <int EPI>
__global__ __launch_bounds__(256, 3) void gemm128(
    const short* __restrict__ A, const short* __restrict__ BT,
    const float* __restrict__ b0, const float* __restrict__ b1, const float* __restrict__ b2,
    void* __restrict__ out0, void* __restrict__ out1, void* __restrict__ out2,
    int M, int N, int K, int lda, int ldb)
{
    __shared__ short lds[16384];          // 32 KB: 4 x 4096 (A0,A1,B0,B1)
    short* As0 = lds;
    short* As1 = lds + 4096;
    short* Bs0 = lds + 8192;
    short* Bs1 = lds + 12288;

    const int tid = threadIdx.x;
    const int lane = tid & 63, w = tid >> 6;
    const int rl = lane & 15, g = lane >> 4;
    const int wr = w >> 1, wc = w & 1;
    const int bid = blockIdx.x;
    int bm, bn;
    if (EPI == 2) {
        int s = bid >> 3;
        bm = (bid & 7) * 16 + s / 6;
        bn = s - (s / 6) * 6;
    } else {
        const int nb = N >> 7;
        bm = bid / nb;
        bn = bid % nb;
    }
    const int m0 = bm << 7, n0 = bn << 7;

    if (EPI == 3) { A += blockIdx.y << 8; BT += blockIdx.y << 8; }

    f32x4 acc[4][4];
#pragma unroll
    for (int m = 0; m < 4; ++m)
#pragma unroll
        for (int n = 0; n < 4; ++n) acc[m][n] = fzero();

    const short* ap = A + (long)(m0 + w * 32 + (lane >> 2)) * lda + ((lane & 3) << 3);
    const short* bp = BT + (long)(n0 + w * 32 + (lane >> 2)) * ldb + ((lane & 3) << 3);
    const int woff = w * 1024;

#define STAGE(dA, dB, kk) do { \
        gl16(ap + (kk), (dA) + woff); \
        gl16(ap + (kk) + 16 * lda, (dA) + woff + 512); \
        gl16(bp + (kk), (dB) + woff); \
        gl16(bp + (kk) + 16 * ldb, (dB) + woff + 512); } while (0)

    const int nt_ = K >> 5;
    STAGE(As0, Bs0, 0);
    for (int t = 0; t < nt_; ++t) {
        const short* cA = (t & 1) ? As1 : As0;
        const short* cB = (t & 1) ? Bs1 : Bs0;
        short* nA = (t & 1) ? As0 : As1;
        short* nB = (t & 1) ? Bs0 : Bs1;
        if (t + 1 < nt_) {
            STAGE(nA, nB, (t + 1) << 5);
            asm volatile("s_waitcnt vmcnt(4)" ::: "memory");   // cur's 4 loads landed
        } else {
            asm volatile("s_waitcnt vmcnt(0)" ::: "memory");
        }
        __builtin_amdgcn_s_barrier();
        half8 af[4], bf[4];
#pragma unroll
        for (int m = 0; m < 4; ++m) af[m] = *(const half8*)&cA[(wr * 64 + m * 16 + rl) * 32 + g * 8];
#pragma unroll
        for (int n = 0; n < 4; ++n) bf[n] = *(const half8*)&cB[(wc * 64 + n * 16 + rl) * 32 + g * 8];
#pragma unroll
        for (int m = 0; m < 4; ++m)
#pragma unroll
            for (int n = 0; n < 4; ++n) acc[m][n] = MFMAH(af[m], bf[n], acc[m][n]);
        __builtin_amdgcn_s_barrier();
    }
#undef STAGE

    if (EPI == 2) {
        // Stage the block's 128x128 output into LDS in FINAL layout, then
        // store fully-coalesced. bn 0-1: q panel. bn 2-3: K tiles. bn 4-5: V tiles.
#pragma unroll
        for (int m = 0; m < 4; ++m)
#pragma unroll
            for (int nt = 0; nt < 4; ++nt) {
                const int cl = wc * 64 + nt * 16 + rl;      // 0..127 within block
                const int col = n0 + cl;
#pragma unroll
                for (int j = 0; j < 4; ++j) {
                    const int tl = wr * 64 + m * 16 + g * 4 + j;   // 0..127
                    float v;
                    int slot;
                    if (bn < 2) {
                        v = (acc[m][nt][j] + b0[col]) * 0.18033688011112042f;  // 0.125*log2e
                        slot = tl * 128 + cl;
                    } else if (bn < 4) {
                        v = acc[m][nt][j] + b1[(bn - 2) * 128 + cl];
                        int hl = cl >> 6, dd = cl & 63;
                        int c = dd >> 4, hi2 = (dd >> 3) & 1, e = dd & 7;
                        int kkl = tl >> 5, l31t = tl & 31;
                        slot = (hl * 4 + kkl) * 2048 + (c * 64 + hi2 * 32 + l31t) * 8 + e;
                    } else {
                        v = acc[m][nt][j] + b2[(bn - 4) * 128 + cl];
                        int hl = cl >> 6, d = cl & 63;
                        int kkl = tl >> 5, chi = (tl >> 4) & 1, hi2 = (tl >> 3) & 1, e = tl & 7;
                        int c = chi * 2 + (d >> 5);
                        slot = (hl * 4 + kkl) * 2048 + (c * 64 + hi2 * 32 + (d & 31)) * 8 + e;
                    }
                    lds[slot] = f2h(v);
                }
            }
        __syncthreads();
        const int bh = m0 >> 10;
        if (bn < 2) {
            short* qo = (short*)out0 + (long)m0 * 256 + n0;
#pragma unroll
            for (int p = 0; p < 8; ++p) {
                int idx = p * 256 + tid, rowl = idx >> 4, ch = idx & 15;
                *(half8*)(qo + rowl * 256 + ch * 8) = *(const half8*)&lds[rowl * 128 + ch * 8];
            }
        } else {
            short* dst = (bn < 4) ? (short*)out1 : (short*)out2;
            const int hb = (bn < 4) ? (bn - 2) * 2 : (bn - 4) * 2;
            const int kk0 = (m0 & 1023) >> 5;
#pragma unroll
            for (int p = 0; p < 8; ++p) {
                int idx = p * 256 + tid, til = idx >> 8, wit = idx & 255;
                int hl = til >> 2, kkl = til & 3;
                long base = (((long)(bh * 4 + hb + hl) * 32) + kk0 + kkl) * 2048;
                *(half8*)(dst + base + wit * 8) = *(const half8*)&lds[til * 2048 + wit * 8];
            }
        }
    } else {  // EPI == 3: fp32 partial
        float* op = (float*)out0 + (long)blockIdx.y * M * N;
#pragma unroll
        for (int m = 0; m < 4; ++m)
#pragma unroll
            for (int nt = 0; nt < 4; ++nt) {
                const int col = n0 + wc * 64 + nt * 16 + rl;
#pragma unroll
                for (int j = 0; j < 4; ++j) {
                    const long grow = m0 + wr * 64 + m * 16 + g * 4 + j;
                    op[grow * N + col] = acc[m][nt][j];
                }
            }
    }
}

// sum split-K partials + bias -> fp32 out
__global__ void reduce_out_k(const float* __restrict__ p, const float* __restrict__ bo,
                             float* __restrict__ out) {
    int i = blockIdx.x * 256 + threadIdx.x;   // 524288
    float s = bo[i & 255];
#pragma unroll
    for (int ks = 0; ks < 8; ++ks) s += p[ks * 524288 + i];
    out[i] = s;
}

// ---------------- flash attention: 3-buffer counted-vmcnt K/V pipeline ----------------

__global__ __launch_bounds__(256) void attn_k(const short* __restrict__ q, const short* __restrict__ kc,
                                              const short* __restrict__ vc, short* __restrict__ oc) {
    __shared__ short kv[12288];   // 24KB: 3 bufs x 4096 shorts ([K 2048 | V 2048])
    const int tid = threadIdx.x;
    const int lane = tid & 63, w = tid >> 6;
    const int l31 = lane & 31, hi = lane >> 5;
    const int bhh = blockIdx.x & 63;          // XCD-local: idx%8 = bhh%8
    const int bh = bhh >> 2, h = bhh & 3;
    const int q0 = (blockIdx.x >> 6) * 128 + w * 32;

    const short* qb = q + (long)bh * 262144 + h * 64;
    const short* kt = kc + (long)bhh * 65536;   // 32 tiles x 2048 shorts
    const short* vt = vc + (long)bhh * 65536;

    half8 qf[4];
#pragma unroll
    for (int c = 0; c < 4; ++c)
        qf[c] = *(const half8*)(qb + (long)(q0 + l31) * 256 + c * 16 + hi * 8);

    float m_ = -1e30f, l_ = 0.f;
    f32x16 O0, O1;
#pragma unroll
    for (int r = 0; r < 16; ++r) { O0[r] = 0.f; O1[r] = 0.f; }

    const int sw = w * 512 + lane * 8;        // per-lane src offset within a tile

#define KVSTAGE(kk, b) do { \
        gl16(kt + (kk) * 2048 + sw, &kv[(b) * 4096 + w * 512]); \
        gl16(vt + (kk) * 2048 + sw, &kv[(b) * 4096 + 2048 + w * 512]); } while (0)

    KVSTAGE(0, 0);
    KVSTAGE(1, 1);
    int bc = 0, bs = 2;
    for (int kk = 0; kk < 32; ++kk) {
        if (kk < 31) asm volatile("s_waitcnt vmcnt(2)" ::: "memory");
        else         asm volatile("s_waitcnt vmcnt(0)" ::: "memory");
        __builtin_amdgcn_s_barrier();
        if (kk + 2 < 32) {
            KVSTAGE(kk + 2, bs);
            bs = (bs == 2) ? 0 : bs + 1;
        }
        const int bb = bc * 4096;
        half8 KD[4], VD[4];
#pragma unroll
        for (int c = 0; c < 4; ++c) {
            KD[c] = *(const half8*)&kv[bb + c * 512 + lane * 8];
            VD[c] = *(const half8*)&kv[bb + 2048 + c * 512 + lane * 8];
        }
        f32x16 S;
#pragma unroll
        for (int r = 0; r < 16; ++r) S[r] = 0.f;
#pragma unroll
        for (int c = 0; c < 4; ++c) S = MFMA32(KD[c], qf[c], S);
        // tree max over 16, then cross-half via permlane32_swap
        float t8[8];
#pragma unroll
        for (int r = 0; r < 8; ++r) t8[r] = fmaxf(S[2 * r], S[2 * r + 1]);
        float mx = fmaxf(fmaxf(fmaxf(t8[0], t8[1]), fmaxf(t8[2], t8[3])),
                         fmaxf(fmaxf(t8[4], t8[5]), fmaxf(t8[6], t8[7])));
        uint2v sp = __builtin_amdgcn_permlane32_swap(f2u(mx), f2u(mx), false, false);
        mx = fmaxf(u2f(sp[0]), u2f(sp[1]));
        if (__any(mx > m_ + 8.f)) {           // defer-max THR=8 (log2 units)
            float mn = fmaxf(m_, mx);
            float sc = exp2f(m_ - mn);
            m_ = mn;
            l_ *= sc;
#pragma unroll
            for (int r = 0; r < 16; ++r) { O0[r] *= sc; O1[r] *= sc; }
        }
        float p[16];
#pragma unroll
        for (int r = 0; r < 16; ++r) p[r] = exp2f(S[r] - m_);
        float s8[8];
#pragma unroll
        for (int r = 0; r < 8; ++r) s8[r] = p[2 * r] + p[2 * r + 1];
        float rs = (((s8[0] + s8[1]) + (s8[2] + s8[3])) + ((s8[4] + s8[5]) + (s8[6] + s8[7])));
        uint2v sq = __builtin_amdgcn_permlane32_swap(f2u(rs), f2u(rs), false, false);
        rs = u2f(sq[0]) + u2f(sq[1]);
        l_ += rs;
        // pack P^T fragments (cvt_pkrtz + permlane32_swap)
        half8 PA[2];
#pragma unroll
        for (int c = 0; c < 2; ++c) {
            const int o = c * 8;
            unsigned a0 = f2u(__builtin_bit_cast(float, __builtin_amdgcn_cvt_pkrtz(p[o + 0], p[o + 1])));
            unsigned b0v = f2u(__builtin_bit_cast(float, __builtin_amdgcn_cvt_pkrtz(p[o + 4], p[o + 5])));
            unsigned a1 = f2u(__builtin_bit_cast(float, __builtin_amdgcn_cvt_pkrtz(p[o + 2], p[o + 3])));
            unsigned b1v = f2u(__builtin_bit_cast(float, __builtin_amdgcn_cvt_pkrtz(p[o + 6], p[o + 7])));
            uint2v r0 = __builtin_amdgcn_permlane32_swap(a0, b0v, false, false);
            uint2v r1 = __builtin_amdgcn_permlane32_swap(a1, b1v, false, false);
            uint4v wpk = {r0[0], r1[0], r0[1], r1[1]};
            PA[c] = __builtin_bit_cast(half8, wpk);
        }
        O0 = MFMA32(VD[0], PA[0], O0);
        O1 = MFMA32(VD[1], PA[0], O1);
        O0 = MFMA32(VD[2], PA[1], O0);
        O1 = MFMA32(VD[3], PA[1], O1);
        bc = (bc == 2) ? 0 : bc + 1;
    }
#undef KVSTAGE

    const float inv = 1.f / l_;
    const int b = bh >> 3, d = bh & 7;
    const int t = q0 + l31;
    short* ob = oc + ((long)(b * 1024 + t) * 8 + d) * 256 + h * 64;
#pragma unroll
    for (int rr = 0; rr < 8; ++rr) {
        int dvb = (rr & 1) * 2 + 8 * (rr >> 1) + 4 * hi;
        unsigned u0 = (unsigned short)f2h(O0[2 * rr] * inv) | ((unsigned)(unsigned short)f2h(O0[2 * rr + 1] * inv) << 16);
        unsigned u1 = (unsigned short)f2h(O1[2 * rr] * inv) | ((unsigned)(unsigned short)f2h(O1[2 * rr + 1] * inv) << 16);
        *(unsigned*)(ob + dvb) = u0;
        *(unsigned*)(ob + 32 + dvb) = u1;
    }
}

// ---------------- launch ----------------

extern "C" void kernel_launch(void* const* d_in, const int* in_sizes, int n_in,
                              void* d_out, int out_size, void* d_ws, size_t ws_size,
                              hipStream_t stream) {
    const float* x     = (const float*)d_in[0];
    const float* Woff1 = (const float*)d_in[1];
    const float* boff1 = (const float*)d_in[2];
    const float* Woff2 = (const float*)d_in[3];
    const float* boff2 = (const float*)d_in[4];
    const float* Wq    = (const float*)d_in[5];
    const float* bq    = (const float*)d_in[6];
    const float* Wk    = (const float*)d_in[7];
    const float* bk    = (const float*)d_in[8];
    const float* Wv    = (const float*)d_in[9];
    const float* bv    = (const float*)d_in[10];
    const float* Wo    = (const float*)d_in[11];
    const float* bo    = (const float*)d_in[12];

    char* ws = (char*)d_ws;
    short* hsplit = (short*)(ws + 0);             // 3,145,728
    short* B2T    = (short*)(ws + 3145728);       // 6,291,456 (end 9,437,184)
    short* cat    = (short*)(ws + 0);             // 8,388,608 (alias; hsplit/B2T dead)
    short* Wtqkv  = (short*)(ws + 9437184);       //   393,216
    short* WtoT   = (short*)(ws + 9830400);       // 1,048,576 (end 10,878,976)
    half4* Qt     = (half4*)(ws + 10878976);      // 4,194,304 (end 15,073,280)
    short* xs     = (short*)(ws + 15073280);      // 8,388,608 (end 23,461,888)
    float* oz     = (float*)(ws + 23461888);      // 33,554,432 (end 57,016,320; dead after sample_k)
    short* qbuf   = (short*)(ws + 23461888);      // 8,388,608 (alias oz)
    short* kcoal  = (short*)(ws + 31850496);      // 8,388,608
    short* vcoal  = (short*)(ws + 40239104);      // 8,388,608 (end 48,627,712)
    float* parts  = (float*)(ws + 48627712);      // 16,777,216 (end 65,404,928)

    // fused prep: W transposes + f16 quad table
    prep_all_k<<<5120, 256, 0, stream>>>(x, Woff2, Wq, Wk, Wv, Wo, B2T, Wtqkv, WtoT, Qt);

    // offset network stage 1: exact fp32 + gelu + fp16 split
    gemm1_k<<<128, 256, 0, stream>>>(x, Woff1, boff1, hsplit);

    // stage 2 GEMM (f16 3-term): z -> fp32 oz
    gemm_off<<<512, 256, 0, stream>>>(hsplit, B2T, boff2, oz);

    // tanh + bilinear resampling at full occupancy
    sample_k<<<2048, 256, 0, stream>>>(oz, Qt, xs);

    // qkv projections (q pre-scaled into exp2 domain; K/V fragment-ordered, LDS-staged stores)
    gemm128<2><<<(16384 / 128) * (768 / 128), 256, 0, stream>>>(
        xs, Wtqkv, bq, bk, bv, qbuf, kcoal, vcoal, 16384, 768, 256, 256, 256);

    // attention (3-buffer counted-vmcnt pipeline, swapped-operand)
    attn_k<<<512, 256, 0, stream>>>(qbuf, kcoal, vcoal, cat);

    // output projection: split-K=8 partials + reduce
    gemm128<3><<<dim3((2048 / 128) * (256 / 128), 8), 256, 0, stream>>>(
        cat, WtoT, nullptr, nullptr, nullptr, parts, nullptr, nullptr, 2048, 256, 256, 2048, 2048);
    reduce_out_k<<<2048, 256, 0, stream>>>(parts, bo, (float*)d_out);
}

// Round 21
// 136.634 us; speedup vs baseline: 1.0308x; 1.0308x over previous
//
#include <hip/hip_runtime.h>
#include <hip/hip_bf16.h>

typedef __attribute__((ext_vector_type(8))) _Float16 half8;   // 8 f16 = 4 VGPRs
typedef __attribute__((ext_vector_type(4))) _Float16 half4;   // 4 f16 = 8 B
typedef __attribute__((ext_vector_type(4))) float f32x4;
typedef __attribute__((ext_vector_type(16))) float f32x16;
typedef __attribute__((ext_vector_type(2))) unsigned uint2v;
typedef __attribute__((ext_vector_type(4))) unsigned uint4v;

#define MFMAH(a, b, c) __builtin_amdgcn_mfma_f32_16x16x32_f16((a), (b), (c), 0, 0, 0)
#define MFMA32(a, b, c) __builtin_amdgcn_mfma_f32_32x32x16_f16((a), (b), (c), 0, 0, 0)

__device__ __forceinline__ short f2h(float v) { _Float16 h = (_Float16)v; return __builtin_bit_cast(short, h); }
__device__ __forceinline__ f32x4 fzero() { f32x4 z = {0.f, 0.f, 0.f, 0.f}; return z; }
__device__ __forceinline__ float u2f(unsigned u) { return __builtin_bit_cast(float, u); }
__device__ __forceinline__ unsigned f2u(float f) { return __builtin_bit_cast(unsigned, f); }

__device__ __forceinline__ void gl16(const void* g, void* l) {
    __builtin_amdgcn_global_load_lds((const __attribute__((address_space(1))) unsigned*)g,
                                     (__attribute__((address_space(3))) unsigned*)l, 16, 0, 0);
}

__device__ __forceinline__ float fast_tanh(float z) {
    // 1 - 2/(e^2z + 1): saturates to exactly +-1.0, err ~1e-6
    float E = __expf(2.f * z);
    return 1.f - 2.f / (E + 1.f);
}

__device__ __forceinline__ float gelu_tanh(float v) {
    float u = 0.7978845608028654f * (v + 0.044715f * v * v * v);
    return 0.5f * v * (1.f + fast_tanh(u));
}

// ---------------- fused prep: W transposes + f16 bilinear quad table ----------------

__global__ __launch_bounds__(256) void prep_all_k(
    const float* __restrict__ x, const float* __restrict__ Woff2,
    const float* __restrict__ Wq, const float* __restrict__ Wk, const float* __restrict__ Wv,
    const float* __restrict__ Wo,
    short* __restrict__ B2T, short* __restrict__ Wtqkv, short* __restrict__ WtoT,
    half4* __restrict__ Q)
{
    __shared__ float t[64][65];
    const int tid = threadIdx.x;
    const int bid = blockIdx.x;
    if (bid < 256) {
        const int bk = bid >> 6, bn = bid & 63;
        const int k0 = bk * 64, n0 = bn * 64;
#pragma unroll
        for (int p = 0; p < 16; ++p) {
            int idx = p * 256 + tid, r = idx >> 6, c = idx & 63;
            t[r][c] = Woff2[(long)(k0 + r) * 4096 + n0 + c];
        }
        __syncthreads();
#pragma unroll
        for (int p = 0; p < 16; ++p) {
            int idx = p * 256 + tid, nr = idx >> 6, kc = idx & 63;
            float v = t[kc][nr];
            _Float16 w1 = (_Float16)v;
            _Float16 w2 = (_Float16)(v - (float)w1);
            long base = (long)(n0 + nr) * 768 + k0 + kc;
            B2T[base]       = __builtin_bit_cast(short, w1);
            B2T[base + 256] = __builtin_bit_cast(short, w1);
            B2T[base + 512] = __builtin_bit_cast(short, w2);
        }
    } else if (bid < 1024) {
        int i = (bid - 256) * 256 + tid;           // 768*256
        int n = i >> 8, k = i & 255;
        const float* s = (n < 256) ? Wq : (n < 512) ? Wk : Wv;
        Wtqkv[i] = f2h(s[k * 256 + (n & 255)]);
    } else if (bid < 3072) {
        int i = (bid - 1024) * 256 + tid;          // 256*2048
        int n = i >> 11, k = i & 2047;
        WtoT[i] = f2h(Wo[k * 256 + n]);
    } else {
        int i = (bid - 3072) * 256 + tid;          // 2*1024*256
        int b = i >> 18, r = (i >> 8) & 1023, c = i & 255;
        const float* xb = x + (b << 18);
        int r1 = (r + 1) & 1023, c1 = (c + 1) & 255;
        half4 qv;
        qv[0] = (_Float16)xb[(r << 8) + c];
        qv[1] = (_Float16)xb[(r << 8) + c1];
        qv[2] = (_Float16)xb[(r1 << 8) + c];
        qv[3] = (_Float16)xb[(r1 << 8) + c1];
        Q[i] = qv;
    }
}

// ---------------- GEMM1: exact fp32, fused gelu + fp16 hi/lo split ----------------

__global__ __launch_bounds__(256) void gemm1_k(const float* __restrict__ x, const float* __restrict__ W,
                                               const float* __restrict__ bias, short* __restrict__ hs) {
    __shared__ float As[64][17];
    __shared__ float Bs[16][68];
    const int tid = threadIdx.x;
    const int bm = blockIdx.x >> 2, bn = blockIdx.x & 3;     // 32 x 4
    const int m0 = bm * 64, n0 = bn * 64;
    const int ty = tid >> 4, tx = tid & 15;
    float acc[4][4] = {};
    const int ar = tid >> 2, ak = (tid & 3) << 2;
    const int bk = tid >> 4, bc = (tid & 15) << 2;

    for (int k0 = 0; k0 < 256; k0 += 16) {
        __syncthreads();
        float4 av = *(const float4*)(x + (m0 + ar) * 256 + k0 + ak);
        As[ar][ak + 0] = av.x; As[ar][ak + 1] = av.y; As[ar][ak + 2] = av.z; As[ar][ak + 3] = av.w;
        *(float4*)&Bs[bk][bc] = *(const float4*)(W + (k0 + bk) * 256 + n0 + bc);
        __syncthreads();
#pragma unroll
        for (int kk = 0; kk < 16; ++kk) {
            float a_[4], b_[4];
#pragma unroll
            for (int i = 0; i < 4; ++i) a_[i] = As[ty * 4 + i][kk];
            *(float4*)b_ = *(const float4*)&Bs[kk][tx * 4];
#pragma unroll
            for (int i = 0; i < 4; ++i)
#pragma unroll
                for (int j = 0; j < 4; ++j) acc[i][j] += a_[i] * b_[j];
        }
    }
#pragma unroll
    for (int i = 0; i < 4; ++i) {
        int row = m0 + ty * 4 + i;
#pragma unroll
        for (int j = 0; j < 4; ++j) {
            int col = n0 + tx * 4 + j;
            float v = gelu_tanh(acc[i][j] + bias[col]);
            _Float16 h1 = (_Float16)v;
            _Float16 h2 = (_Float16)(v - (float)h1);
            hs[row * 768 + col]       = __builtin_bit_cast(short, h1);
            hs[row * 768 + 256 + col] = __builtin_bit_cast(short, h2);
            hs[row * 768 + 512 + col] = __builtin_bit_cast(short, h1);
        }
    }
}

// ---------------- offset GEMM + sampler: 128x128, sync quad gathers (plateau config) ----------------

__global__ __launch_bounds__(256, 3) void gemm_samp(
    const short* __restrict__ A, const short* __restrict__ BT,
    const float* __restrict__ b0, short* __restrict__ out0, const half4* __restrict__ Q)
{
    __shared__ short lds[16384];          // 32 KB
    short* As0 = lds;
    short* As1 = lds + 4096;
    short* Bs0 = lds + 8192;
    short* Bs1 = lds + 12288;

    const int tid = threadIdx.x;
    const int lane = tid & 63, w = tid >> 6;
    const int rl = lane & 15, g = lane >> 4;
    const int wr = w >> 1, wc = w & 1;
    const int bid = blockIdx.x;
    const int g2 = bid & 7, s = bid >> 3;
    const int bm = (g2 >> 2) * 8 + (s >> 3);
    const int bn = (g2 & 3) * 8 + (s & 7);
    const int m0 = bm << 7, n0 = bn << 7;

    f32x4 acc[4][4];
#pragma unroll
    for (int m = 0; m < 4; ++m)
#pragma unroll
        for (int n = 0; n < 4; ++n) acc[m][n] = fzero();

    const short* ap = A + (long)(m0 + w * 32 + (lane >> 2)) * 768 + ((lane & 3) << 3);
    const short* bp = BT + (long)(n0 + w * 32 + (lane >> 2)) * 768 + ((lane & 3) << 3);
    const int woff = w * 1024;

#define STAGE(dA, dB, kk) do { \
        gl16(ap + (kk), (dA) + woff); \
        gl16(ap + (kk) + 16 * 768, (dA) + woff + 512); \
        gl16(bp + (kk), (dB) + woff); \
        gl16(bp + (kk) + 16 * 768, (dB) + woff + 512); } while (0)

    STAGE(As0, Bs0, 0);
    for (int t = 0; t < 24; ++t) {
        const short* cA = (t & 1) ? As1 : As0;
        const short* cB = (t & 1) ? Bs1 : Bs0;
        short* nA = (t & 1) ? As0 : As1;
        short* nB = (t & 1) ? Bs0 : Bs1;
        if (t + 1 < 24) {
            STAGE(nA, nB, (t + 1) << 5);
            asm volatile("s_waitcnt vmcnt(4)" ::: "memory");
        } else {
            asm volatile("s_waitcnt vmcnt(0)" ::: "memory");
        }
        __builtin_amdgcn_s_barrier();
        half8 af[4], bf[4];
#pragma unroll
        for (int m = 0; m < 4; ++m) af[m] = *(const half8*)&cA[(wr * 64 + m * 16 + rl) * 32 + g * 8];
#pragma unroll
        for (int n = 0; n < 4; ++n) bf[n] = *(const half8*)&cB[(wc * 64 + n * 16 + rl) * 32 + g * 8];
#pragma unroll
        for (int m = 0; m < 4; ++m)
#pragma unroll
            for (int n = 0; n < 4; ++n) acc[m][n] = MFMAH(af[m], bf[n], acc[m][n]);
        __builtin_amdgcn_s_barrier();
    }
#undef STAGE

    // epilogue: tanh -> f16-quad bilinear into LDS [128][72], coalesced stores
    const int jlo = (rl & 1) ? 2 : 0;
#pragma unroll
    for (int m = 0; m < 4; ++m)
#pragma unroll
        for (int nt = 0; nt < 4; ++nt) {
            const int col = n0 + wc * 64 + nt * 16 + rl;
            float o4[4], po4[4];
            const float bb = b0[col];
#pragma unroll
            for (int j = 0; j < 4; ++j) o4[j] = fast_tanh(acc[m][nt][j] + bb);
#pragma unroll
            for (int j = 0; j < 4; ++j) po4[j] = __shfl_xor(o4[j], 1);
            const int cl = (wc * 64 + nt * 16 + rl) >> 1;
#pragma unroll
            for (int u = 0; u < 2; ++u) {
                const int j = jlo + u;
                float gx = (((rl & 1) ? po4[j] : o4[j]) + 1.f) * 127.5f;    // [0,255]
                float gy = (((rl & 1) ? o4[j] : po4[j]) + 1.f) * 4095.5f;   // [0,8191]
                float x0f = floorf(gx), y0f = floorf(gy);
                float wx = gx - x0f, wy = gy - y0f;
                int ix0 = (int)x0f, iy0 = (int)y0f;
                const int rowl = wr * 64 + m * 16 + g * 4 + j;
                const int b = (m0 + rowl) >> 10;
                half4 qv = Q[((long)b << 18) + ((iy0 & 1023) << 8) + ix0];
                float r = (float)qv[0] * (1.f - wy) * (1.f - wx) + (float)qv[1] * (1.f - wy) * wx
                        + (float)qv[2] * wy * (1.f - wx) + (float)qv[3] * wy * wx;
                lds[rowl * 72 + cl] = f2h(r);
            }
        }
    __syncthreads();
    // coalesced stores: 128 rows x 128B
    const int d = n0 >> 9, c0 = (n0 >> 1) & 255;
    const int b = m0 >> 10, t0 = m0 & 1023;
    short* xo = out0 + ((long)(b * 8 + d) * 1024 + t0) * 256 + c0;
#pragma unroll
    for (int p = 0; p < 4; ++p) {
        int idx = p * 256 + tid, rowl = idx >> 3, ch = idx & 7;
        *(half8*)(xo + rowl * 256 + ch * 8) = *(const half8*)&lds[rowl * 72 + ch * 8];
    }
}

// ---------------- 128x128 MFMA GEMM, counted-vmcnt double-buffered staging ----------------
// EPI 2: qkv scatter, LDS-staged final layouts
// EPI 3: fp32 split-K partial (blockIdx.y = ks, K-chunk 512)

template <int EPI>
__global__ __launch_bounds__(256, 3) void gemm128(
    const short* __restrict__ A, const short* __restrict__ BT,
    const float* __restrict__ b0, const float* __restrict__ b1, const float* __restrict__ b2,
    void* __restrict__ out0, void* __restrict__ out1, void* __restrict__ out2,
    int M, int N, int K, int lda, int ldb)
{
    __shared__ short lds[16384];          // 32 KB: 4 x 4096 (A0,A1,B0,B1)
    short* As0 = lds;
    short* As1 = lds + 4096;
    short* Bs0 = lds + 8192;
    short* Bs1 = lds + 12288;

    const int tid = threadIdx.x;
    const int lane = tid & 63, w = tid >> 6;
    const int rl = lane & 15, g = lane >> 4;
    const int wr = w >> 1, wc = w & 1;
    const int bid = blockIdx.x;
    int bm, bn;
    if (EPI == 2) {
        int s = bid >> 3;
        bm = (bid & 7) * 16 + s / 6;
        bn = s - (s / 6) * 6;
    } else {
        const int nb = N >> 7;
        bm = bid / nb;
        bn = bid % nb;
    }
    const int m0 = bm << 7, n0 = bn << 7;

    if (EPI == 3) { A += blockIdx.y << 9; BT += blockIdx.y << 9; }

    f32x4 acc[4][4];
#pragma unroll
    for (int m = 0; m < 4; ++m)
#pragma unroll
        for (int n = 0; n < 4; ++n) acc[m][n] = fzero();

    const short* ap = A + (long)(m0 + w * 32 + (lane >> 2)) * lda + ((lane & 3) << 3);
    const short* bp = BT + (long)(n0 + w * 32 + (lane >> 2)) * ldb + ((lane & 3) << 3);
    const int woff = w * 1024;

#define STAGE(dA, dB, kk) do { \
        gl16(ap + (kk), (dA) + woff); \
        gl16(ap + (kk) + 16 * lda, (dA) + woff + 512); \
        gl16(bp + (kk), (dB) + woff); \
        gl16(bp + (kk) + 16 * ldb, (dB) + woff + 512); } while (0)

    const int nt_ = K >> 5;
    STAGE(As0, Bs0, 0);
    for (int t = 0; t < nt_; ++t) {
        const short* cA = (t & 1) ? As1 : As0;
        const short* cB = (t & 1) ? Bs1 : Bs0;
        short* nA = (t & 1) ? As0 : As1;
        short* nB = (t & 1) ? Bs0 : Bs1;
        if (t + 1 < nt_) {
            STAGE(nA, nB, (t + 1) << 5);
            asm volatile("s_waitcnt vmcnt(4)" ::: "memory");   // cur's 4 loads landed
        } else {
            asm volatile("s_waitcnt vmcnt(0)" ::: "memory");
        }
        __builtin_amdgcn_s_barrier();
        half8 af[4], bf[4];
#pragma unroll
        for (int m = 0; m < 4; ++m) af[m] = *(const half8*)&cA[(wr * 64 + m * 16 + rl) * 32 + g * 8];
#pragma unroll
        for (int n = 0; n < 4; ++n) bf[n] = *(const half8*)&cB[(wc * 64 + n * 16 + rl) * 32 + g * 8];
#pragma unroll
        for (int m = 0; m < 4; ++m)
#pragma unroll
            for (int n = 0; n < 4; ++n) acc[m][n] = MFMAH(af[m], bf[n], acc[m][n]);
        __builtin_amdgcn_s_barrier();
    }
#undef STAGE

    if (EPI == 2) {
        // Stage the block's 128x128 output into LDS in FINAL layout, then
        // store fully-coalesced. bn 0-1: q panel. bn 2-3: K tiles. bn 4-5: V tiles.
#pragma unroll
        for (int m = 0; m < 4; ++m)
#pragma unroll
            for (int nt = 0; nt < 4; ++nt) {
                const int cl = wc * 64 + nt * 16 + rl;      // 0..127 within block
                const int col = n0 + cl;
#pragma unroll
                for (int j = 0; j < 4; ++j) {
                    const int tl = wr * 64 + m * 16 + g * 4 + j;   // 0..127
                    float v;
                    int slot;
                    if (bn < 2) {
                        v = (acc[m][nt][j] + b0[col]) * 0.18033688011112042f;  // 0.125*log2e
                        slot = tl * 128 + cl;
                    } else if (bn < 4) {
                        v = acc[m][nt][j] + b1[(bn - 2) * 128 + cl];
                        int hl = cl >> 6, dd = cl & 63;
                        int c = dd >> 4, hi2 = (dd >> 3) & 1, e = dd & 7;
                        int kkl = tl >> 5, l31t = tl & 31;
                        slot = (hl * 4 + kkl) * 2048 + (c * 64 + hi2 * 32 + l31t) * 8 + e;
                    } else {
                        v = acc[m][nt][j] + b2[(bn - 4) * 128 + cl];
                        int hl = cl >> 6, d = cl & 63;
                        int kkl = tl >> 5, chi = (tl >> 4) & 1, hi2 = (tl >> 3) & 1, e = tl & 7;
                        int c = chi * 2 + (d >> 5);
                        slot = (hl * 4 + kkl) * 2048 + (c * 64 + hi2 * 32 + (d & 31)) * 8 + e;
                    }
                    lds[slot] = f2h(v);
                }
            }
        __syncthreads();
        const int bh = m0 >> 10;
        if (bn < 2) {
            short* qo = (short*)out0 + (long)m0 * 256 + n0;
#pragma unroll
            for (int p = 0; p < 8; ++p) {
                int idx = p * 256 + tid, rowl = idx >> 4, ch = idx & 15;
                *(half8*)(qo + rowl * 256 + ch * 8) = *(const half8*)&lds[rowl * 128 + ch * 8];
            }
        } else {
            short* dst = (bn < 4) ? (short*)out1 : (short*)out2;
            const int hb = (bn < 4) ? (bn - 2) * 2 : (bn - 4) * 2;
            const int kk0 = (m0 & 1023) >> 5;
#pragma unroll
            for (int p = 0; p < 8; ++p) {
                int idx = p * 256 + tid, til = idx >> 8, wit = idx & 255;
                int hl = til >> 2, kkl = til & 3;
                long base = (((long)(bh * 4 + hb + hl) * 32) + kk0 + kkl) * 2048;
                *(half8*)(dst + base + wit * 8) = *(const half8*)&lds[til * 2048 + wit * 8];
            }
        }
    } else {  // EPI == 3: fp32 partial
        float* op = (float*)out0 + (long)blockIdx.y * M * N;
#pragma unroll
        for (int m = 0; m < 4; ++m)
#pragma unroll
            for (int nt = 0; nt < 4; ++nt) {
                const int col = n0 + wc * 64 + nt * 16 + rl;
#pragma unroll
                for (int j = 0; j < 4; ++j) {
                    const long grow = m0 + wr * 64 + m * 16 + g * 4 + j;
                    op[grow * N + col] = acc[m][nt][j];
                }
            }
    }
}

// sum split-K partials + bias -> fp32 out
__global__ void reduce_out_k(const float* __restrict__ p, const float* __restrict__ bo,
                             float* __restrict__ out) {
    int i = blockIdx.x * 256 + threadIdx.x;   // 524288
    float s = bo[i & 255];
#pragma unroll
    for (int ks = 0; ks < 4; ++ks) s += p[ks * 524288 + i];
    out[i] = s;
}

// ---------------- flash attention: 3-buffer counted-vmcnt K/V pipeline ----------------

__global__ __launch_bounds__(256) void attn_k(const short* __restrict__ q, const short* __restrict__ kc,
                                              const short* __restrict__ vc, short* __restrict__ oc) {
    __shared__ short kv[12288];   // 24KB: 3 bufs x 4096 shorts ([K 2048 | V 2048])
    const int tid = threadIdx.x;
    const int lane = tid & 63, w = tid >> 6;
    const int l31 = lane & 31, hi = lane >> 5;
    const int bhh = blockIdx.x & 63;          // XCD-local: idx%8 = bhh%8
    const int bh = bhh >> 2, h = bhh & 3;
    const int q0 = (blockIdx.x >> 6) * 128 + w * 32;

    const short* qb = q + (long)bh * 262144 + h * 64;
    const short* kt = kc + (long)bhh * 65536;   // 32 tiles x 2048 shorts
    const short* vt = vc + (long)bhh * 65536;

    half8 qf[4];
#pragma unroll
    for (int c = 0; c < 4; ++c)
        qf[c] = *(const half8*)(qb + (long)(q0 + l31) * 256 + c * 16 + hi * 8);

    float m_ = -1e30f, l_ = 0.f;
    f32x16 O0, O1;
#pragma unroll
    for (int r = 0; r < 16; ++r) { O0[r] = 0.f; O1[r] = 0.f; }

    const int sw = w * 512 + lane * 8;        // per-lane src offset within a tile

#define KVSTAGE(kk, b) do { \
        gl16(kt + (kk) * 2048 + sw, &kv[(b) * 4096 + w * 512]); \
        gl16(vt + (kk) * 2048 + sw, &kv[(b) * 4096 + 2048 + w * 512]); } while (0)

    KVSTAGE(0, 0);
    KVSTAGE(1, 1);
    int bc = 0, bs = 2;
    for (int kk = 0; kk < 32; ++kk) {
        if (kk < 31) asm volatile("s_waitcnt vmcnt(2)" ::: "memory");
        else         asm volatile("s_waitcnt vmcnt(0)" ::: "memory");
        __builtin_amdgcn_s_barrier();
        if (kk + 2 < 32) {
            KVSTAGE(kk + 2, bs);
            bs = (bs == 2) ? 0 : bs + 1;
        }
        const int bb = bc * 4096;
        half8 KD[4], VD[4];
#pragma unroll
        for (int c = 0; c < 4; ++c) {
            KD[c] = *(const half8*)&kv[bb + c * 512 + lane * 8];
            VD[c] = *(const half8*)&kv[bb + 2048 + c * 512 + lane * 8];
        }
        f32x16 S;
#pragma unroll
        for (int r = 0; r < 16; ++r) S[r] = 0.f;
#pragma unroll
        for (int c = 0; c < 4; ++c) S = MFMA32(KD[c], qf[c], S);
        // tree max over 16, then cross-half via permlane32_swap
        float t8[8];
#pragma unroll
        for (int r = 0; r < 8; ++r) t8[r] = fmaxf(S[2 * r], S[2 * r + 1]);
        float mx = fmaxf(fmaxf(fmaxf(t8[0], t8[1]), fmaxf(t8[2], t8[3])),
                         fmaxf(fmaxf(t8[4], t8[5]), fmaxf(t8[6], t8[7])));
        uint2v sp = __builtin_amdgcn_permlane32_swap(f2u(mx), f2u(mx), false, false);
        mx = fmaxf(u2f(sp[0]), u2f(sp[1]));
        if (__any(mx > m_ + 8.f)) {           // defer-max THR=8 (log2 units)
            float mn = fmaxf(m_, mx);
            float sc = exp2f(m_ - mn);
            m_ = mn;
            l_ *= sc;
#pragma unroll
            for (int r = 0; r < 16; ++r) { O0[r] *= sc; O1[r] *= sc; }
        }
        float p[16];
#pragma unroll
        for (int r = 0; r < 16; ++r) p[r] = exp2f(S[r] - m_);
        float s8[8];
#pragma unroll
        for (int r = 0; r < 8; ++r) s8[r] = p[2 * r] + p[2 * r + 1];
        float rs = (((s8[0] + s8[1]) + (s8[2] + s8[3])) + ((s8[4] + s8[5]) + (s8[6] + s8[7])));
        uint2v sq = __builtin_amdgcn_permlane32_swap(f2u(rs), f2u(rs), false, false);
        rs = u2f(sq[0]) + u2f(sq[1]);
        l_ += rs;
        // pack P^T fragments (cvt_pkrtz + permlane32_swap)
        half8 PA[2];
#pragma unroll
        for (int c = 0; c < 2; ++c) {
            const int o = c * 8;
            unsigned a0 = f2u(__builtin_bit_cast(float, __builtin_amdgcn_cvt_pkrtz(p[o + 0], p[o + 1])));
            unsigned b0v = f2u(__builtin_bit_cast(float, __builtin_amdgcn_cvt_pkrtz(p[o + 4], p[o + 5])));
            unsigned a1 = f2u(__builtin_bit_cast(float, __builtin_amdgcn_cvt_pkrtz(p[o + 2], p[o + 3])));
            unsigned b1v = f2u(__builtin_bit_cast(float, __builtin_amdgcn_cvt_pkrtz(p[o + 6], p[o + 7])));
            uint2v r0 = __builtin_amdgcn_permlane32_swap(a0, b0v, false, false);
            uint2v r1 = __builtin_amdgcn_permlane32_swap(a1, b1v, false, false);
            uint4v wpk = {r0[0], r1[0], r0[1], r1[1]};
            PA[c] = __builtin_bit_cast(half8, wpk);
        }
        O0 = MFMA32(VD[0], PA[0], O0);
        O1 = MFMA32(VD[1], PA[0], O1);
        O0 = MFMA32(VD[2], PA[1], O0);
        O1 = MFMA32(VD[3], PA[1], O1);
        bc = (bc == 2) ? 0 : bc + 1;
    }
#undef KVSTAGE

    const float inv = 1.f / l_;
    const int b = bh >> 3, d = bh & 7;
    const int t = q0 + l31;
    short* ob = oc + ((long)(b * 1024 + t) * 8 + d) * 256 + h * 64;
#pragma unroll
    for (int rr = 0; rr < 8; ++rr) {
        int dvb = (rr & 1) * 2 + 8 * (rr >> 1) + 4 * hi;
        unsigned u0 = (unsigned short)f2h(O0[2 * rr] * inv) | ((unsigned)(unsigned short)f2h(O0[2 * rr + 1] * inv) << 16);
        unsigned u1 = (unsigned short)f2h(O1[2 * rr] * inv) | ((unsigned)(unsigned short)f2h(O1[2 * rr + 1] * inv) << 16);
        *(unsigned*)(ob + dvb) = u0;
        *(unsigned*)(ob + 32 + dvb) = u1;
    }
}

// ---------------- launch ----------------

extern "C" void kernel_launch(void* const* d_in, const int* in_sizes, int n_in,
                              void* d_out, int out_size, void* d_ws, size_t ws_size,
                              hipStream_t stream) {
    const float* x     = (const float*)d_in[0];
    const float* Woff1 = (const float*)d_in[1];
    const float* boff1 = (const float*)d_in[2];
    const float* Woff2 = (const float*)d_in[3];
    const float* boff2 = (const float*)d_in[4];
    const float* Wq    = (const float*)d_in[5];
    const float* bq    = (const float*)d_in[6];
    const float* Wk    = (const float*)d_in[7];
    const float* bk    = (const float*)d_in[8];
    const float* Wv    = (const float*)d_in[9];
    const float* bv    = (const float*)d_in[10];
    const float* Wo    = (const float*)d_in[11];
    const float* bo    = (const float*)d_in[12];

    char* ws = (char*)d_ws;
    short* hsplit = (short*)(ws + 0);             // 3,145,728
    short* B2T    = (short*)(ws + 3145728);       // 6,291,456 (end 9,437,184)
    short* cat    = (short*)(ws + 0);             // 8,388,608 (alias; hsplit/B2T dead)
    short* Wtqkv  = (short*)(ws + 9437184);       //   393,216
    short* WtoT   = (short*)(ws + 9830400);       // 1,048,576 (end 10,878,976)
    half4* Qt     = (half4*)(ws + 10878976);      // 4,194,304 (end 15,073,280)
    short* xs     = (short*)(ws + 15073280);      // 8,388,608 (end 23,461,888)
    short* qbuf   = (short*)(ws + 23461888);      // 8,388,608
    short* kcoal  = (short*)(ws + 31850496);      // 8,388,608
    short* vcoal  = (short*)(ws + 40239104);      // 8,388,608 (end 48,627,712)
    float* parts  = (float*)(ws + 48627712);      // 4*2048*256*4 = 8,388,608 (end 57,016,320)

    // fused prep: W transposes + f16 quad table
    prep_all_k<<<5120, 256, 0, stream>>>(x, Woff2, Wq, Wk, Wv, Wo, B2T, Wtqkv, WtoT, Qt);

    // offset network stage 1: exact fp32 + gelu + fp16 split
    gemm1_k<<<128, 256, 0, stream>>>(x, Woff1, boff1, hsplit);

    // stage 2 (f16 3-term) + fused tanh + quad-gather bilinear resampling
    gemm_samp<<<512, 256, 0, stream>>>(hsplit, B2T, boff2, xs, Qt);

    // qkv projections (q pre-scaled into exp2 domain; K/V fragment-ordered, LDS-staged stores)
    gemm128<2><<<(16384 / 128) * (768 / 128), 256, 0, stream>>>(
        xs, Wtqkv, bq, bk, bv, qbuf, kcoal, vcoal, 16384, 768, 256, 256, 256);

    // attention (3-buffer counted-vmcnt pipeline, swapped-operand)
    attn_k<<<512, 256, 0, stream>>>(qbuf, kcoal, vcoal, cat);

    // output projection: split-K=4 partials + reduce
    gemm128<3><<<dim3((2048 / 128) * (256 / 128), 4), 256, 0, stream>>>(
        cat, WtoT, nullptr, nullptr, nullptr, parts, nullptr, nullptr, 2048, 256, 512, 2048, 2048);
    reduce_out_k<<<2048, 256, 0, stream>>>(parts, bo, (float*)d_out);
}